// Round 10
// baseline (205.983 us; speedup 1.0000x reference)
//
#include <hip/hip_runtime.h>
#include <hip/hip_bf16.h>

typedef __hip_bfloat16 bf16;

#define N_NODES 100000
#define N_EDGES 1600000
#define F_IN    128
#define F_OUT   64
#define NBLK    391   // ceil(100000/256)

#define NB_BKT   196    // buckets of 512 target-nodes (c>>9)
#define BKT_SH   9
#define BKT_CAP  8960   // expected 8163/bucket, +8.8 sigma
#define LBIN_CAP 56     // per-block LDS bin cap (expected 20.9, +7.7 sigma)
#define EPB_A    4096   // edges per block, phase A (8 edges/thread @512 thr)
#define WBLK     16     // weights blocks inside FAT1 (= F_IN*F_OUT/512)
#define XMZ_BLK  782    // ceil(100000/128) xmz blocks inside FAT2

// ---------------- CSR-path workspace layout (bytes) ----------------
// flag @0 (256) | dinv f32 @256 (400KB) | M @400,384 | cvec @433,152
// cnt @433,664 | ptr @833,664 | gtail @1,233,664 (784B)
// srcs int @1,238,528 (6.4MB, ends 7,638,528)
// z bf16 @8,038,400 (12.8MB, ends 20,838,400)  [z = x@M, UNSCALED]
// Mhi bf16 @20,838,400 (16KB) | Mlo bf16 @20,854,784 (16KB)
// bkt u32 @20,871,168 (7.02MB, ends 27,895,808)  [no z-alias: build||xmz overlap]
// total 27,895,808 B. Fallback (atomic multi-pass) path used if ws smaller.
//
// LESSONS (R5, R7): per-edge random global 4B stores OR atomics cost ~40-64B
// each in HBM/coherence amplification. All per-edge scatter work stays
// LDS-staged; global atomics only at block granularity.
// LESSON (R9): binA was latency-bound at 6.6 waves/CU with a 16-edge serial
// LDS-atomic chain/thread -> 512-thread blocks (8-edge chain, 12.7 waves/CU).
// Structure: memset(gtail) -> FAT1{weights || binA}@512thr ->
//            FAT2{build || xmz(z unscaled)} -> agg(16-wide, dinv FMA).

typedef __attribute__((ext_vector_type(8))) short vbf8;   // 8 bf16 = 4 VGPR
typedef __attribute__((ext_vector_type(4))) float vf4;

__device__ __forceinline__ float ldf(const void* p, size_t i, bool isbf) {
    return isbf ? __bfloat162float(((const bf16*)p)[i]) : ((const float*)p)[i];
}
__device__ __forceinline__ void stf(void* p, size_t i, bool isbf, float v) {
    if (isbf) ((bf16*)p)[i] = __float2bfloat16(v);
    else      ((float*)p)[i] = v;
}
__device__ __forceinline__ unsigned short f2bfu(float f) {
    __hip_bfloat16 h = __float2bfloat16(f);
    union { __hip_bfloat16 h; unsigned short u; } c; c.h = h; return c.u;
}
__device__ __forceinline__ float bflo(unsigned int u) { return __uint_as_float(u << 16); }
__device__ __forceinline__ float bfhi(unsigned int u) { return __uint_as_float(u & 0xffff0000u); }

// ===================== FAT1 (512 thr): weights-part || binA-part ============
// blocks [0,WBLK): M = Wg @ Wf^T, cvec, Mhi/Mlo frag-order split, flag (blk 0).
// blocks [WBLK, WBLK+391): edge bucketize (LDS bins, coalesced flush),
//   8 edges/thread (2 int4 pairs) — half the serial LDS-atomic chain of 256thr.
// NO per-edge global atomics (R7 lesson). gtail pre-zeroed by memset node.
// Mhi/Mlo layout: frag element i of lane l, tile (kk,ct) at ((kk*4+ct)*64+l)*8+i
//   holds M[kk*32 + 8*((l>>4)&3) + i][ct*16 + (l&15)]; same (l>>4,i)->k bijection
//   as the xmz A-side loads, so contraction is HW-k-order independent.
__global__ __launch_bounds__(512) void k_fat1(const unsigned short* __restrict__ xs,
                          const void* __restrict__ Wg, const void* __restrict__ bg,
                          const void* __restrict__ Wf, const void* __restrict__ bfc,
                          float* __restrict__ M, float* __restrict__ cvec,
                          bf16* __restrict__ Mhi, bf16* __restrict__ Mlo,
                          int* __restrict__ flag,
                          const int* __restrict__ ei, int* __restrict__ gtail,
                          unsigned* __restrict__ bkt) {
    __shared__ unsigned lbin[NB_BKT * LBIN_CAP];
    __shared__ int lcnt[NB_BKT];
    __shared__ int lbase[NB_BKT];
    __shared__ int sflag;
    int lt = threadIdx.x;

    if (blockIdx.x < WBLK) {
        // ---------------- weights part ----------------
        if (lt < 64) {                       // wave 0: local dtype sniff
            int good = 0;
#pragma unroll
            for (int q = 0; q < 2; ++q) {
                unsigned short v = xs[2 * (lt + 64 * q)];
                int e = (v >> 7) & 0xFF;
                if ((e >= 100 && e <= 140) || ((v & 0x7FFF) == 0)) good++;
            }
            unsigned long long m1 = __ballot(good >= 1), m2 = __ballot(good >= 2);
            if (lt == 0) sflag = (__popcll(m1) + __popcll(m2) >= 96) ? 1 : 0;
        }
        __syncthreads();
        bool isbf = (sflag != 0);
        if (blockIdx.x == 0 && lt == 0) *flag = sflag;
        int t = blockIdx.x * 512 + lt;
        if (t >= F_IN * F_OUT) return;
        int k = t >> 6, c = t & 63;
        float s = 0.f;
        for (int j = 0; j < F_IN; ++j)
            s += ldf(Wg, k * F_IN + j, isbf) * ldf(Wf, c * F_IN + j, isbf);
        M[k * F_OUT + c] = s;
        if (Mhi) {
            int l    = (((k >> 3) & 3) << 4) | (c & 15);
            int fidx = ((((k >> 5) << 2) + (c >> 4)) * 64 + l) * 8 + (k & 7);
            bf16 h  = __float2bfloat16(s);
            Mhi[fidx] = h;
            Mlo[fidx] = __float2bfloat16(s - __bfloat162float(h));
        }
        if (k == 0) {
            float cs = ldf(bfc, c, isbf);
            for (int j = 0; j < F_IN; ++j)
                cs += ldf(bg, j, isbf) * ldf(Wf, c * F_IN + j, isbf);
            cvec[c] = cs;
        }
        return;
    }

    // ---------------- binA part ----------------
    int t = lt;
    for (int b = t; b < NB_BKT; b += 512) lcnt[b] = 0;
    __syncthreads();
    int v0 = (blockIdx.x - WBLK) * (EPB_A / 4);     // int4-vector index base
#pragma unroll
    for (int q = 0; q < 2; ++q) {
        int vi = v0 + q * 512 + t;
        if (vi * 4 < N_EDGES) {            // N_EDGES % 4 == 0: whole-vector guard
            int4 rv = ((const int4*)ei)[vi];
            int4 cv = ((const int4*)(ei + N_EDGES))[vi];
            int rs[4] = {rv.x, rv.y, rv.z, rv.w};
            int cs[4] = {cv.x, cv.y, cv.z, cv.w};
#pragma unroll
            for (int j = 0; j < 4; ++j) {
                int r = rs[j], c = cs[j];
                int b = c >> BKT_SH;
                unsigned val = (unsigned)r | ((unsigned)(c & ((1 << BKT_SH) - 1)) << 17);
                int p = atomicAdd(&lcnt[b], 1);
                if (p < LBIN_CAP) {
                    lbin[b * LBIN_CAP + p] = val;
                } else {                          // rare overflow: direct global
                    int gp = atomicAdd(&gtail[b], 1);
                    if (gp < BKT_CAP) bkt[(size_t)b * BKT_CAP + gp] = val;
                }
            }
        }
    }
    __syncthreads();
    for (int b = t; b < NB_BKT; b += 512) {
        int n = min(lcnt[b], LBIN_CAP);
        lbase[b] = atomicAdd(&gtail[b], n);
    }
    __syncthreads();
    // flush: wave w owns bins w, w+8, ... (8 waves @ 512 thr)
    int w = t >> 6, l = t & 63;
    for (int b = w; b < NB_BKT; b += 8) {
        int nB = min(lcnt[b], LBIN_CAP);
        int gp0 = lbase[b];
        for (int i = l; i < nB; i += 64) {
            int gp = gp0 + i;
            if (gp < BKT_CAP) bkt[(size_t)b * BKT_CAP + gp] = lbin[b * LBIN_CAP + i];
        }
    }
}

// ===================== FAT2: build-part || xmz-part =====================
// blocks [0,NB_BKT): per-bucket base (gtail reduce) -> LDS histogram -> scan
//   -> ptr/cnt/dinv -> place srcs (LDS-windowed scatter).
// blocks [NB_BKT, NB_BKT+XMZ_BLK): z = x@M via MFMA, 512 thr / 128 rows.
//   z is UNSCALED (dinv applied in k_agg) — no dependence on the build part;
//   the two halves overlap freely across CUs.
__global__ __launch_bounds__(512) void k_fat2(const unsigned* __restrict__ bkt,
                                              const int* __restrict__ gtail,
                                              int* __restrict__ ptr,
                                              int* __restrict__ cnt,
                                              float* __restrict__ dinv,
                                              int* __restrict__ srcs,
                                              const int* __restrict__ flag,
                                              const void* __restrict__ x,
                                              const bf16* __restrict__ Mhi,
                                              const bf16* __restrict__ Mlo,
                                              bf16* __restrict__ z) {
    __shared__ int cntl[512], sm[512], fill[512];
    int t = threadIdx.x;

    if (blockIdx.x < NB_BKT) {
        // ---------------- build part ----------------
        int b = blockIdx.x;
        int n = min(gtail[b], BKT_CAP);
        // base = sum_{b'<b} min(gtail[b'], BKT_CAP): 512-wide masked tree reduce
        int gv = (t < b) ? min(gtail[t], BKT_CAP) : 0;   // t<b<=195 implies t<NB_BKT
        sm[t] = gv; __syncthreads();
#pragma unroll
        for (int s = 256; s >= 1; s >>= 1) {
            if (t < s) sm[t] += sm[t + s];
            __syncthreads();
        }
        int base = sm[0];
        cntl[t] = 0;
        __syncthreads();
        for (int i = t; i < n; i += 512)
            atomicAdd(&cntl[bkt[(size_t)b * BKT_CAP + i] >> 17], 1);
        __syncthreads();
        int v = cntl[t];
        sm[t] = v; __syncthreads();
        for (int s = 1; s < 512; s <<= 1) {
            int add = (t >= s) ? sm[t - s] : 0;
            __syncthreads();
            sm[t] += add;
            __syncthreads();
        }
        int excl = sm[t] - v;
        fill[t] = excl;
        int node = (b << BKT_SH) + t;
        if (node < N_NODES) {
            ptr[node]  = base + excl;
            cnt[node]  = v;
            dinv[node] = rsqrtf((float)(v + 1));   // +1 self-loop
        }
        __syncthreads();
        for (int i = t; i < n; i += 512) {
            unsigned e = bkt[(size_t)b * BKT_CAP + i];
            int c = (int)(e >> 17);
            int p = atomicAdd(&fill[c], 1);        // LDS atomic
            srcs[base + p] = (int)(e & 0x1FFFF);
        }
        return;
    }

    // ---------------- xmz part (512 thr, 128 rows/block) ----------------
    // bf16 world: A frags straight from x, 2 MFMAs/tile (Mh,Ml).
    // fp32 world: trunc-split xh+xl (~2^-16), 3 MFMAs/tile (xh*Mh+xh*Ml+xl*Mh).
    // D layout (m89-verified): col = lane&15, row = (lane>>4)*4 + reg.
    int bid = blockIdx.x - NB_BKT;
    int w = t >> 6, lane = t & 63;
    int g = lane >> 4, cb = lane & 15;
    int r0 = bid * 128 + w * 16;          // wave's 16-row base
    int rr = min(r0 + cb, N_NODES - 1);   // A-fragment row (clamped dup for tail)
    bool isbf = (*flag != 0);
    const vbf8* Bh = (const vbf8*)Mhi;
    const vbf8* Bl = (const vbf8*)Mlo;
    vf4 acc0 = {0.f,0.f,0.f,0.f}, acc1 = {0.f,0.f,0.f,0.f};
    vf4 acc2 = {0.f,0.f,0.f,0.f}, acc3 = {0.f,0.f,0.f,0.f};

    if (isbf) {
        const vbf8* X8 = (const vbf8*)x;
#pragma unroll
        for (int kk = 0; kk < 4; ++kk) {
            vbf8 a = X8[(size_t)rr * 16 + kk * 4 + g];   // row rr, k = 32kk + 8g + [0..7]
            int bb = kk * 256 + lane;                    // (kk*4 + ct)*64 + lane
            acc0 = __builtin_amdgcn_mfma_f32_16x16x32_bf16(a, Bh[bb      ], acc0, 0, 0, 0);
            acc0 = __builtin_amdgcn_mfma_f32_16x16x32_bf16(a, Bl[bb      ], acc0, 0, 0, 0);
            acc1 = __builtin_amdgcn_mfma_f32_16x16x32_bf16(a, Bh[bb +  64], acc1, 0, 0, 0);
            acc1 = __builtin_amdgcn_mfma_f32_16x16x32_bf16(a, Bl[bb +  64], acc1, 0, 0, 0);
            acc2 = __builtin_amdgcn_mfma_f32_16x16x32_bf16(a, Bh[bb + 128], acc2, 0, 0, 0);
            acc2 = __builtin_amdgcn_mfma_f32_16x16x32_bf16(a, Bl[bb + 128], acc2, 0, 0, 0);
            acc3 = __builtin_amdgcn_mfma_f32_16x16x32_bf16(a, Bh[bb + 192], acc3, 0, 0, 0);
            acc3 = __builtin_amdgcn_mfma_f32_16x16x32_bf16(a, Bl[bb + 192], acc3, 0, 0, 0);
        }
    } else {
        const float4* X4 = (const float4*)x;
#pragma unroll
        for (int kk = 0; kk < 4; ++kk) {
            float4 v0 = X4[(size_t)rr * 32 + kk * 8 + g * 2];      // k = 32kk+8g+[0..3]
            float4 v1 = X4[(size_t)rr * 32 + kk * 8 + g * 2 + 1];  // k = 32kk+8g+[4..7]
            vbf8 ah, al;
            {
                float fv[8] = {v0.x, v0.y, v0.z, v0.w, v1.x, v1.y, v1.z, v1.w};
#pragma unroll
                for (int i = 0; i < 8; ++i) {
                    unsigned bi = __float_as_uint(fv[i]);
                    ah[i] = (short)(bi >> 16);                         // trunc hi
                    float r = fv[i] - __uint_as_float(bi & 0xffff0000u);
                    al[i] = (short)(__float_as_uint(r) >> 16);         // trunc lo
                }
            }
            int bb = kk * 256 + lane;
            vbf8 b0h = Bh[bb      ], b0l = Bl[bb      ];
            vbf8 b1h = Bh[bb +  64], b1l = Bl[bb +  64];
            vbf8 b2h = Bh[bb + 128], b2l = Bl[bb + 128];
            vbf8 b3h = Bh[bb + 192], b3l = Bl[bb + 192];
            acc0 = __builtin_amdgcn_mfma_f32_16x16x32_bf16(ah, b0h, acc0, 0, 0, 0);
            acc0 = __builtin_amdgcn_mfma_f32_16x16x32_bf16(ah, b0l, acc0, 0, 0, 0);
            acc0 = __builtin_amdgcn_mfma_f32_16x16x32_bf16(al, b0h, acc0, 0, 0, 0);
            acc1 = __builtin_amdgcn_mfma_f32_16x16x32_bf16(ah, b1h, acc1, 0, 0, 0);
            acc1 = __builtin_amdgcn_mfma_f32_16x16x32_bf16(ah, b1l, acc1, 0, 0, 0);
            acc1 = __builtin_amdgcn_mfma_f32_16x16x32_bf16(al, b1h, acc1, 0, 0, 0);
            acc2 = __builtin_amdgcn_mfma_f32_16x16x32_bf16(ah, b2h, acc2, 0, 0, 0);
            acc2 = __builtin_amdgcn_mfma_f32_16x16x32_bf16(ah, b2l, acc2, 0, 0, 0);
            acc2 = __builtin_amdgcn_mfma_f32_16x16x32_bf16(al, b2h, acc2, 0, 0, 0);
            acc3 = __builtin_amdgcn_mfma_f32_16x16x32_bf16(ah, b3h, acc3, 0, 0, 0);
            acc3 = __builtin_amdgcn_mfma_f32_16x16x32_bf16(ah, b3l, acc3, 0, 0, 0);
            acc3 = __builtin_amdgcn_mfma_f32_16x16x32_bf16(al, b3h, acc3, 0, 0, 0);
        }
    }

    unsigned short* zb = (unsigned short*)z;
#pragma unroll
    for (int i = 0; i < 4; ++i) {
        int r = r0 + g * 4 + i;           // D row
        if (r < N_NODES) {
            unsigned short* zr = zb + (size_t)r * F_OUT + cb;
            zr[0]  = f2bfu(acc0[i]);
            zr[16] = f2bfu(acc1[i]);
            zr[32] = f2bfu(acc2[i]);
            zr[48] = f2bfu(acc3[i]);
        }
    }
}

// pull aggregation v6: 8 nodes per wave, 16 edges in flight per iteration
// (two srcs words per lane -> 2x memory-level parallelism; typical degree ~16
// completes in one iteration). z unscaled; acc += dinv[su]*z[su].
__global__ __launch_bounds__(256) void k_agg(const int* __restrict__ flag,
                                             const int* __restrict__ ptr,
                                             const int* __restrict__ cnt,
                                             const int* __restrict__ srcs,
                                             const float* __restrict__ dinv,
                                             const bf16* __restrict__ z,
                                             const float* __restrict__ cvec,
                                             void* __restrict__ out) {
    int wid  = (blockIdx.x * 256 + threadIdx.x) >> 6;
    int lane = threadIdx.x & 63;
    int g  = lane >> 3;          // node slot in wave
    int j8 = lane & 7;           // feature octet
    int node = wid * 8 + g;      // grid sized so node <= 99999 always when wid valid
    bool alive = node < N_NODES;
    int n = 0, start = 0;
    if (alive) { n = cnt[node]; start = ptr[node]; }
    const uint4* z4 = (const uint4*)z;

    float acc[8];
#pragma unroll
    for (int i = 0; i < 8; ++i) acc[i] = 0.f;

    for (int b = 0; __any(b < n); b += 16) {
        int s0 = 0, s1 = 0;
        int i0 = b + j8, i1 = b + 8 + j8;
        if (i0 < n) s0 = srcs[start + i0];   // lane (g,j8): edges b+j8, b+8+j8
        if (i1 < n) s1 = srcs[start + i1];
#pragma unroll
        for (int k = 0; k < 8; ++k) {
            int su = __shfl(s0, (g << 3) | k, 64);
            if (b + k < n) {
                float ds = dinv[su];
                uint4 v = z4[(size_t)su * 8 + j8];
                acc[0] += ds * bflo(v.x); acc[1] += ds * bfhi(v.x);
                acc[2] += ds * bflo(v.y); acc[3] += ds * bfhi(v.y);
                acc[4] += ds * bflo(v.z); acc[5] += ds * bfhi(v.z);
                acc[6] += ds * bflo(v.w); acc[7] += ds * bfhi(v.w);
            }
        }
#pragma unroll
        for (int k = 0; k < 8; ++k) {
            int su = __shfl(s1, (g << 3) | k, 64);
            if (b + 8 + k < n) {
                float ds = dinv[su];
                uint4 v = z4[(size_t)su * 8 + j8];
                acc[0] += ds * bflo(v.x); acc[1] += ds * bfhi(v.x);
                acc[2] += ds * bflo(v.y); acc[3] += ds * bfhi(v.y);
                acc[4] += ds * bflo(v.z); acc[5] += ds * bfhi(v.z);
                acc[6] += ds * bflo(v.w); acc[7] += ds * bfhi(v.w);
            }
        }
    }

    if (!alive) return;
    bool isbf = (*flag != 0);
    uint4 sv = z4[(size_t)node * 8 + j8];   // self-loop row (unscaled)
    float dn = dinv[node];
    const float4* cv4 = (const float4*)cvec;
    float4 c0 = cv4[j8 * 2], c1 = cv4[j8 * 2 + 1];
    size_t ob = (size_t)node * F_OUT + j8 * 8;
    if (isbf) {
        ushort4 p0, p1;
        p0.x = f2bfu(dn * (acc[0] + dn * bflo(sv.x)) + c0.x);
        p0.y = f2bfu(dn * (acc[1] + dn * bfhi(sv.x)) + c0.y);
        p0.z = f2bfu(dn * (acc[2] + dn * bflo(sv.y)) + c0.z);
        p0.w = f2bfu(dn * (acc[3] + dn * bfhi(sv.y)) + c0.w);
        p1.x = f2bfu(dn * (acc[4] + dn * bflo(sv.z)) + c1.x);
        p1.y = f2bfu(dn * (acc[5] + dn * bfhi(sv.z)) + c1.y);
        p1.z = f2bfu(dn * (acc[6] + dn * bflo(sv.w)) + c1.z);
        p1.w = f2bfu(dn * (acc[7] + dn * bfhi(sv.w)) + c1.w);
        ushort4* ob4 = (ushort4*)((unsigned short*)out + ob);
        ob4[0] = p0; ob4[1] = p1;
    } else {
        float4 q0, q1;
        q0.x = dn * (acc[0] + dn * bflo(sv.x)) + c0.x;
        q0.y = dn * (acc[1] + dn * bfhi(sv.x)) + c0.y;
        q0.z = dn * (acc[2] + dn * bflo(sv.y)) + c0.z;
        q0.w = dn * (acc[3] + dn * bfhi(sv.y)) + c0.w;
        q1.x = dn * (acc[4] + dn * bflo(sv.z)) + c1.x;
        q1.y = dn * (acc[5] + dn * bfhi(sv.z)) + c1.y;
        q1.z = dn * (acc[6] + dn * bflo(sv.w)) + c1.z;
        q1.w = dn * (acc[7] + dn * bfhi(sv.w)) + c1.w;
        float4* of4 = (float4*)((float*)out + ob);
        of4[0] = q0; of4[1] = q1;
    }
}

// ===================== fallback (atomic multi-pass) path =====================

__global__ void k_init_deg(float* __restrict__ deg) {
    int i = blockIdx.x * blockDim.x + threadIdx.x;
    if (i < N_NODES) deg[i] = 1.0f;
}
__global__ void k_deg(const int* __restrict__ col, float* __restrict__ deg) {
    int e = blockIdx.x * blockDim.x + threadIdx.x;
    if (e < N_EDGES) atomicAdd(&deg[col[e]], 1.0f);
}
__global__ void k_dinv(float* __restrict__ deg) {
    int i = blockIdx.x * blockDim.x + threadIdx.x;
    if (i < N_NODES) deg[i] = rsqrtf(deg[i]);
}
__global__ __launch_bounds__(256) void k_xm(const int* __restrict__ flag,
                                            const void* __restrict__ x,
                                            const float* __restrict__ M,
                                            void* __restrict__ z) {
    __shared__ float Ms[F_IN * F_OUT];
    int t = threadIdx.x;
    for (int i = t; i < F_IN * F_OUT; i += 256) Ms[i] = M[i];
    __syncthreads();
    bool isbf = (*flag != 0);
    int r = blockIdx.x * 4 + (t >> 6);
    int c = t & 63;
    if (r >= N_NODES) return;
    float s = 0.f;
    if (isbf) {
        const bf16* xr = (const bf16*)x + (size_t)r * F_IN;
#pragma unroll
        for (int k = 0; k < F_IN; ++k) s += __bfloat162float(xr[k]) * Ms[k * F_OUT + c];
    } else {
        const float* xr = (const float*)x + (size_t)r * F_IN;
#pragma unroll
        for (int k = 0; k < F_IN; ++k) s += xr[k] * Ms[k * F_OUT + c];
    }
    stf(z, (size_t)r * F_OUT + c, isbf, s);
}
template <int LOGF>
__global__ __launch_bounds__(256) void k_init_acc(const int* __restrict__ flag,
                                                  const float* __restrict__ dinv,
                                                  const void* __restrict__ z,
                                                  float* __restrict__ acc, int base) {
    bool isbf = (*flag != 0);
    int t = blockIdx.x * 256 + threadIdx.x;
    int i = t >> LOGF, f = t & ((1 << LOGF) - 1);
    if (i >= N_NODES) return;
    float d = dinv[i];
    acc[t] = d * d * ldf(z, (size_t)i * F_OUT + base + f, isbf);
}
template <int LOGF>
__global__ __launch_bounds__(256) void k_scatter(const int* __restrict__ flag,
                                                 const int* __restrict__ ei,
                                                 const float* __restrict__ dinv,
                                                 const void* __restrict__ z,
                                                 float* __restrict__ acc, int base) {
    bool isbf = (*flag != 0);
    long long t = (long long)blockIdx.x * 256 + threadIdx.x;
    int e = (int)(t >> LOGF), f = (int)(t & ((1 << LOGF) - 1));
    if (e >= N_EDGES) return;
    int r = ei[e], c = ei[N_EDGES + e];
    float nm = dinv[r] * dinv[c];
    float v  = nm * ldf(z, (size_t)r * F_OUT + base + f, isbf);
    atomicAdd(&acc[((size_t)c << LOGF) + f], v);
}
template <int LOGF>
__global__ __launch_bounds__(256) void k_final(const int* __restrict__ flag,
                                               const float* __restrict__ acc,
                                               const float* __restrict__ cvec,
                                               void* __restrict__ out, int base) {
    bool isbf = (*flag != 0);
    int t = blockIdx.x * 256 + threadIdx.x;
    int i = t >> LOGF, f = t & ((1 << LOGF) - 1);
    if (i >= N_NODES) return;
    stf(out, (size_t)i * F_OUT + base + f, isbf, acc[t] + cvec[base + f]);
}
template <int LOGF>
static void run_passes(const int* flag, const int* ei, const float* dinv,
                       const void* z, float* acc, const float* cvec, void* out,
                       hipStream_t stream) {
    const int fpp = 1 << LOGF;
    const long long tn = (long long)N_NODES * fpp;
    const long long te = (long long)N_EDGES * fpp;
    const int gn = (int)((tn + 255) / 256);
    const int ge = (int)((te + 255) / 256);
    for (int base = 0; base < F_OUT; base += fpp) {
        k_init_acc<LOGF><<<gn, 256, 0, stream>>>(flag, dinv, z, acc, base);
        k_scatter<LOGF><<<ge, 256, 0, stream>>>(flag, ei, dinv, z, acc, base);
        k_final<LOGF><<<gn, 256, 0, stream>>>(flag, acc, cvec, out, base);
    }
}

extern "C" void kernel_launch(void* const* d_in, const int* in_sizes, int n_in,
                              void* d_out, int out_size, void* d_ws, size_t ws_size,
                              hipStream_t stream) {
    const void* x   = d_in[0];
    const int*  ei  = (const int*)d_in[1];
    const void* Wg  = d_in[2];
    const void* bg  = d_in[3];
    const void* Wf  = d_in[4];
    const void* bfc = d_in[5];
    char* ws = (char*)d_ws;

    const size_t CSR_NEED = 27895808;
    if (ws_size >= CSR_NEED) {
        int*      flag  = (int*)(ws + 0);
        float*    dinv  = (float*)(ws + 256);
        float*    M     = (float*)(ws + 400384);
        float*    cvec  = (float*)(ws + 433152);
        int*      cnt   = (int*)(ws + 433664);
        int*      ptr   = (int*)(ws + 833664);
        int*      gtail = (int*)(ws + 1233664);
        int*      srcs  = (int*)(ws + 1238528);
        bf16*     z     = (bf16*)(ws + 8038400);
        bf16*     Mhi   = (bf16*)(ws + 20838400);
        bf16*     Mlo   = (bf16*)(ws + 20854784);
        unsigned* bkt   = (unsigned*)(ws + 20871168);

        hipMemsetAsync(gtail, 0, NB_BKT * 4, stream);
        // FAT1: 16 weights blocks || 391 binA blocks (512 thr)
        k_fat1<<<WBLK + (N_EDGES + EPB_A - 1) / EPB_A, 512, 0, stream>>>(
                    (const unsigned short*)x, Wg, bg, Wf, bfc, M, cvec, Mhi, Mlo,
                    flag, ei, gtail, bkt);
        // FAT2: 196 build blocks || 782 xmz blocks (512 thr)
        k_fat2<<<NB_BKT + XMZ_BLK, 512, 0, stream>>>(bkt, gtail, ptr, cnt, dinv,
                    srcs, flag, x, Mhi, Mlo, z);
        // 8 nodes per wave: 12500 waves = 3125 blocks of 256
        k_agg<<<3125, 256, 0, stream>>>(flag, ptr, cnt, srcs, dinv, z, cvec, d_out);
    } else {
        int*   flag = (int*)(ws + 0);
        float* deg  = (float*)(ws + 256);
        float* M    = (float*)(ws + 400384);
        float* cvec = (float*)(ws + 433152);
        float* acc  = (float*)(ws + 433664);

        // weights-only FAT1 (grid = WBLK -> binA part never runs)
        k_fat1<<<WBLK, 512, 0, stream>>>((const unsigned short*)x,
                    Wg, bg, Wf, bfc, M, cvec, (bf16*)nullptr, (bf16*)nullptr,
                    flag, (const int*)nullptr, (int*)nullptr, (unsigned*)nullptr);
        k_init_deg<<<NBLK, 256, 0, stream>>>(deg);
        k_deg<<<N_EDGES / 256, 256, 0, stream>>>(ei + N_EDGES, deg);
        k_dinv<<<NBLK, 256, 0, stream>>>(deg);
        k_xm<<<N_NODES / 4, 256, 0, stream>>>(flag, x, M, d_out);
        const size_t bn = 433664;
        if      (ws_size >= bn + (400000ull << 6)) run_passes<6>(flag, ei, deg, d_out, acc, cvec, d_out, stream);
        else if (ws_size >= bn + (400000ull << 5)) run_passes<5>(flag, ei, deg, d_out, acc, cvec, d_out, stream);
        else if (ws_size >= bn + (400000ull << 4)) run_passes<4>(flag, ei, deg, d_out, acc, cvec, d_out, stream);
        else if (ws_size >= bn + (400000ull << 3)) run_passes<3>(flag, ei, deg, d_out, acc, cvec, d_out, stream);
        else if (ws_size >= bn + (400000ull << 2)) run_passes<2>(flag, ei, deg, d_out, acc, cvec, d_out, stream);
        else if (ws_size >= bn + (400000ull << 1)) run_passes<1>(flag, ei, deg, d_out, acc, cvec, d_out, stream);
        else                                       run_passes<0>(flag, ei, deg, d_out, acc, cvec, d_out, stream);
    }
}

// Round 11
// 202.274 us; speedup vs baseline: 1.0183x; 1.0183x over previous
//
#include <hip/hip_runtime.h>
#include <hip/hip_bf16.h>

typedef __hip_bfloat16 bf16;

#define N_NODES 100000
#define N_EDGES 1600000
#define F_IN    128
#define F_OUT   64
#define NBLK    391   // ceil(100000/256)

#define NB_BKT   196    // buckets of 512 target-nodes (c>>9)
#define BKT_SH   9
#define BKT_CAP  8960   // expected 8163/bucket, +8.8 sigma
#define LBIN_CAP 32     // per-block LDS bin cap (expected 10.45, P(>32)~2e-7)
#define EPB_A    2048   // edges per block, phase A (8 edges/thread @256 thr)
#define WBLK     32     // weights blocks inside FAT1 (= F_IN*F_OUT/256)
#define XMZ_BLK  782    // ceil(100000/128) xmz blocks inside FAT2

// ---------------- CSR-path workspace layout (bytes) ----------------
// flag @0 (256) | dinv f32 @256 (400KB) | M @400,384 | cvec @433,152
// cnt @433,664 | ptr @833,664 | gtail @1,233,664 (784B)
// srcs int @1,238,528 (6.4MB, ends 7,638,528)
// z bf16 @8,038,400 (12.8MB, ends 20,838,400)  [z = x@M, UNSCALED]
// Mhi bf16 @20,838,400 (16KB) | Mlo bf16 @20,854,784 (16KB)
// bkt u32 @20,871,168 (7.02MB, ends 27,895,808)  [no z-alias: build||xmz overlap]
// total 27,895,808 B. Fallback (atomic multi-pass) path used if ws smaller.
//
// LESSONS (R5, R7): per-edge random global 4B stores OR atomics cost ~40-64B
// each in HBM/coherence amplification. All per-edge scatter work stays
// LDS-staged; global atomics only at block granularity.
// LESSON (R10): 512-thr binA blocks REGRESSED (42.5->52.9us) — wider blocks
// double concurrent same-bin LDS-atomic contention. Scale binA by MORE BLOCKS
// (smaller EPB_A, smaller LBIN_CAP -> less LDS -> more blocks/CU), not wider.
// Structure: memset(gtail) -> FAT1{weights || binA}@256thr/2048edges ->
//            FAT2{build || xmz(z unscaled)} -> agg(16-wide, dinv FMA).

typedef __attribute__((ext_vector_type(8))) short vbf8;   // 8 bf16 = 4 VGPR
typedef __attribute__((ext_vector_type(4))) float vf4;

__device__ __forceinline__ float ldf(const void* p, size_t i, bool isbf) {
    return isbf ? __bfloat162float(((const bf16*)p)[i]) : ((const float*)p)[i];
}
__device__ __forceinline__ void stf(void* p, size_t i, bool isbf, float v) {
    if (isbf) ((bf16*)p)[i] = __float2bfloat16(v);
    else      ((float*)p)[i] = v;
}
__device__ __forceinline__ unsigned short f2bfu(float f) {
    __hip_bfloat16 h = __float2bfloat16(f);
    union { __hip_bfloat16 h; unsigned short u; } c; c.h = h; return c.u;
}
__device__ __forceinline__ float bflo(unsigned int u) { return __uint_as_float(u << 16); }
__device__ __forceinline__ float bfhi(unsigned int u) { return __uint_as_float(u & 0xffff0000u); }

// ===================== FAT1 (256 thr): weights-part || binA-part ============
// blocks [0,WBLK): M = Wg @ Wf^T, cvec, Mhi/Mlo frag-order split, flag (blk 0).
// blocks [WBLK, WBLK+782): edge bucketize (LDS bins, coalesced flush),
//   2048 edges/block = 8/thread; 26.7KB LDS -> ~3 blocks/CU resident.
// NO per-edge global atomics (R7 lesson). gtail pre-zeroed by memset node.
// Mhi/Mlo layout: frag element i of lane l, tile (kk,ct) at ((kk*4+ct)*64+l)*8+i
//   holds M[kk*32 + 8*((l>>4)&3) + i][ct*16 + (l&15)]; same (l>>4,i)->k bijection
//   as the xmz A-side loads, so contraction is HW-k-order independent.
__global__ __launch_bounds__(256) void k_fat1(const unsigned short* __restrict__ xs,
                          const void* __restrict__ Wg, const void* __restrict__ bg,
                          const void* __restrict__ Wf, const void* __restrict__ bfc,
                          float* __restrict__ M, float* __restrict__ cvec,
                          bf16* __restrict__ Mhi, bf16* __restrict__ Mlo,
                          int* __restrict__ flag,
                          const int* __restrict__ ei, int* __restrict__ gtail,
                          unsigned* __restrict__ bkt) {
    __shared__ unsigned lbin[NB_BKT * LBIN_CAP];
    __shared__ int lcnt[NB_BKT];
    __shared__ int lbase[NB_BKT];
    __shared__ int sflag;
    int lt = threadIdx.x;

    if (blockIdx.x < WBLK) {
        // ---------------- weights part ----------------
        if (lt < 64) {                       // wave 0: local dtype sniff
            int good = 0;
#pragma unroll
            for (int q = 0; q < 2; ++q) {
                unsigned short v = xs[2 * (lt + 64 * q)];
                int e = (v >> 7) & 0xFF;
                if ((e >= 100 && e <= 140) || ((v & 0x7FFF) == 0)) good++;
            }
            unsigned long long m1 = __ballot(good >= 1), m2 = __ballot(good >= 2);
            if (lt == 0) sflag = (__popcll(m1) + __popcll(m2) >= 96) ? 1 : 0;
        }
        __syncthreads();
        bool isbf = (sflag != 0);
        if (blockIdx.x == 0 && lt == 0) *flag = sflag;
        int t = blockIdx.x * 256 + lt;
        int k = t >> 6, c = t & 63;
        float s = 0.f;
        for (int j = 0; j < F_IN; ++j)
            s += ldf(Wg, k * F_IN + j, isbf) * ldf(Wf, c * F_IN + j, isbf);
        M[k * F_OUT + c] = s;
        if (Mhi) {
            int l    = (((k >> 3) & 3) << 4) | (c & 15);
            int fidx = ((((k >> 5) << 2) + (c >> 4)) * 64 + l) * 8 + (k & 7);
            bf16 h  = __float2bfloat16(s);
            Mhi[fidx] = h;
            Mlo[fidx] = __float2bfloat16(s - __bfloat162float(h));
        }
        if (k == 0) {
            float cs = ldf(bfc, c, isbf);
            for (int j = 0; j < F_IN; ++j)
                cs += ldf(bg, j, isbf) * ldf(Wf, c * F_IN + j, isbf);
            cvec[c] = cs;
        }
        return;
    }

    // ---------------- binA part ----------------
    int t = lt;
    for (int b = t; b < NB_BKT; b += 256) lcnt[b] = 0;
    __syncthreads();
    int v0 = (blockIdx.x - WBLK) * (EPB_A / 4);     // int4-vector index base
#pragma unroll
    for (int q = 0; q < 2; ++q) {
        int vi = v0 + q * 256 + t;
        if (vi * 4 < N_EDGES) {            // N_EDGES % 4 == 0: whole-vector guard
            int4 rv = ((const int4*)ei)[vi];
            int4 cv = ((const int4*)(ei + N_EDGES))[vi];
            int rs[4] = {rv.x, rv.y, rv.z, rv.w};
            int cs[4] = {cv.x, cv.y, cv.z, cv.w};
#pragma unroll
            for (int j = 0; j < 4; ++j) {
                int r = rs[j], c = cs[j];
                int b = c >> BKT_SH;
                unsigned val = (unsigned)r | ((unsigned)(c & ((1 << BKT_SH) - 1)) << 17);
                int p = atomicAdd(&lcnt[b], 1);
                if (p < LBIN_CAP) {
                    lbin[b * LBIN_CAP + p] = val;
                } else {                          // rare overflow: direct global
                    int gp = atomicAdd(&gtail[b], 1);
                    if (gp < BKT_CAP) bkt[(size_t)b * BKT_CAP + gp] = val;
                }
            }
        }
    }
    __syncthreads();
    for (int b = t; b < NB_BKT; b += 256) {
        int n = min(lcnt[b], LBIN_CAP);
        lbase[b] = atomicAdd(&gtail[b], n);
    }
    __syncthreads();
    // flush: wave w owns bins w, w+4, ... (no integer division)
    int w = t >> 6, l = t & 63;
    for (int b = w; b < NB_BKT; b += 4) {
        int nB = min(lcnt[b], LBIN_CAP);
        int gp0 = lbase[b];
        for (int i = l; i < nB; i += 64) {
            int gp = gp0 + i;
            if (gp < BKT_CAP) bkt[(size_t)b * BKT_CAP + gp] = lbin[b * LBIN_CAP + i];
        }
    }
}

// ===================== FAT2: build-part || xmz-part =====================
// blocks [0,NB_BKT): per-bucket base (gtail reduce) -> LDS histogram -> scan
//   -> ptr/cnt/dinv -> place srcs (LDS-windowed scatter).
// blocks [NB_BKT, NB_BKT+XMZ_BLK): z = x@M via MFMA, 512 thr / 128 rows.
//   z is UNSCALED (dinv applied in k_agg) — no dependence on the build part;
//   the two halves overlap freely across CUs.
__global__ __launch_bounds__(512) void k_fat2(const unsigned* __restrict__ bkt,
                                              const int* __restrict__ gtail,
                                              int* __restrict__ ptr,
                                              int* __restrict__ cnt,
                                              float* __restrict__ dinv,
                                              int* __restrict__ srcs,
                                              const int* __restrict__ flag,
                                              const void* __restrict__ x,
                                              const bf16* __restrict__ Mhi,
                                              const bf16* __restrict__ Mlo,
                                              bf16* __restrict__ z) {
    __shared__ int cntl[512], sm[512], fill[512];
    int t = threadIdx.x;

    if (blockIdx.x < NB_BKT) {
        // ---------------- build part ----------------
        int b = blockIdx.x;
        int n = min(gtail[b], BKT_CAP);
        // base = sum_{b'<b} min(gtail[b'], BKT_CAP): 512-wide masked tree reduce
        int gv = (t < b) ? min(gtail[t], BKT_CAP) : 0;   // t<b<=195 implies t<NB_BKT
        sm[t] = gv; __syncthreads();
#pragma unroll
        for (int s = 256; s >= 1; s >>= 1) {
            if (t < s) sm[t] += sm[t + s];
            __syncthreads();
        }
        int base = sm[0];
        cntl[t] = 0;
        __syncthreads();
        for (int i = t; i < n; i += 512)
            atomicAdd(&cntl[bkt[(size_t)b * BKT_CAP + i] >> 17], 1);
        __syncthreads();
        int v = cntl[t];
        sm[t] = v; __syncthreads();
        for (int s = 1; s < 512; s <<= 1) {
            int add = (t >= s) ? sm[t - s] : 0;
            __syncthreads();
            sm[t] += add;
            __syncthreads();
        }
        int excl = sm[t] - v;
        fill[t] = excl;
        int node = (b << BKT_SH) + t;
        if (node < N_NODES) {
            ptr[node]  = base + excl;
            cnt[node]  = v;
            dinv[node] = rsqrtf((float)(v + 1));   // +1 self-loop
        }
        __syncthreads();
        for (int i = t; i < n; i += 512) {
            unsigned e = bkt[(size_t)b * BKT_CAP + i];
            int c = (int)(e >> 17);
            int p = atomicAdd(&fill[c], 1);        // LDS atomic
            srcs[base + p] = (int)(e & 0x1FFFF);
        }
        return;
    }

    // ---------------- xmz part (512 thr, 128 rows/block) ----------------
    // bf16 world: A frags straight from x, 2 MFMAs/tile (Mh,Ml).
    // fp32 world: trunc-split xh+xl (~2^-16), 3 MFMAs/tile (xh*Mh+xh*Ml+xl*Mh).
    // D layout (m89-verified): col = lane&15, row = (lane>>4)*4 + reg.
    int bid = blockIdx.x - NB_BKT;
    int w = t >> 6, lane = t & 63;
    int g = lane >> 4, cb = lane & 15;
    int r0 = bid * 128 + w * 16;          // wave's 16-row base
    int rr = min(r0 + cb, N_NODES - 1);   // A-fragment row (clamped dup for tail)
    bool isbf = (*flag != 0);
    const vbf8* Bh = (const vbf8*)Mhi;
    const vbf8* Bl = (const vbf8*)Mlo;
    vf4 acc0 = {0.f,0.f,0.f,0.f}, acc1 = {0.f,0.f,0.f,0.f};
    vf4 acc2 = {0.f,0.f,0.f,0.f}, acc3 = {0.f,0.f,0.f,0.f};

    if (isbf) {
        const vbf8* X8 = (const vbf8*)x;
#pragma unroll
        for (int kk = 0; kk < 4; ++kk) {
            vbf8 a = X8[(size_t)rr * 16 + kk * 4 + g];   // row rr, k = 32kk + 8g + [0..7]
            int bb = kk * 256 + lane;                    // (kk*4 + ct)*64 + lane
            acc0 = __builtin_amdgcn_mfma_f32_16x16x32_bf16(a, Bh[bb      ], acc0, 0, 0, 0);
            acc0 = __builtin_amdgcn_mfma_f32_16x16x32_bf16(a, Bl[bb      ], acc0, 0, 0, 0);
            acc1 = __builtin_amdgcn_mfma_f32_16x16x32_bf16(a, Bh[bb +  64], acc1, 0, 0, 0);
            acc1 = __builtin_amdgcn_mfma_f32_16x16x32_bf16(a, Bl[bb +  64], acc1, 0, 0, 0);
            acc2 = __builtin_amdgcn_mfma_f32_16x16x32_bf16(a, Bh[bb + 128], acc2, 0, 0, 0);
            acc2 = __builtin_amdgcn_mfma_f32_16x16x32_bf16(a, Bl[bb + 128], acc2, 0, 0, 0);
            acc3 = __builtin_amdgcn_mfma_f32_16x16x32_bf16(a, Bh[bb + 192], acc3, 0, 0, 0);
            acc3 = __builtin_amdgcn_mfma_f32_16x16x32_bf16(a, Bl[bb + 192], acc3, 0, 0, 0);
        }
    } else {
        const float4* X4 = (const float4*)x;
#pragma unroll
        for (int kk = 0; kk < 4; ++kk) {
            float4 v0 = X4[(size_t)rr * 32 + kk * 8 + g * 2];      // k = 32kk+8g+[0..3]
            float4 v1 = X4[(size_t)rr * 32 + kk * 8 + g * 2 + 1];  // k = 32kk+8g+[4..7]
            vbf8 ah, al;
            {
                float fv[8] = {v0.x, v0.y, v0.z, v0.w, v1.x, v1.y, v1.z, v1.w};
#pragma unroll
                for (int i = 0; i < 8; ++i) {
                    unsigned bi = __float_as_uint(fv[i]);
                    ah[i] = (short)(bi >> 16);                         // trunc hi
                    float r = fv[i] - __uint_as_float(bi & 0xffff0000u);
                    al[i] = (short)(__float_as_uint(r) >> 16);         // trunc lo
                }
            }
            int bb = kk * 256 + lane;
            vbf8 b0h = Bh[bb      ], b0l = Bl[bb      ];
            vbf8 b1h = Bh[bb +  64], b1l = Bl[bb +  64];
            vbf8 b2h = Bh[bb + 128], b2l = Bl[bb + 128];
            vbf8 b3h = Bh[bb + 192], b3l = Bl[bb + 192];
            acc0 = __builtin_amdgcn_mfma_f32_16x16x32_bf16(ah, b0h, acc0, 0, 0, 0);
            acc0 = __builtin_amdgcn_mfma_f32_16x16x32_bf16(ah, b0l, acc0, 0, 0, 0);
            acc0 = __builtin_amdgcn_mfma_f32_16x16x32_bf16(al, b0h, acc0, 0, 0, 0);
            acc1 = __builtin_amdgcn_mfma_f32_16x16x32_bf16(ah, b1h, acc1, 0, 0, 0);
            acc1 = __builtin_amdgcn_mfma_f32_16x16x32_bf16(ah, b1l, acc1, 0, 0, 0);
            acc1 = __builtin_amdgcn_mfma_f32_16x16x32_bf16(al, b1h, acc1, 0, 0, 0);
            acc2 = __builtin_amdgcn_mfma_f32_16x16x32_bf16(ah, b2h, acc2, 0, 0, 0);
            acc2 = __builtin_amdgcn_mfma_f32_16x16x32_bf16(ah, b2l, acc2, 0, 0, 0);
            acc2 = __builtin_amdgcn_mfma_f32_16x16x32_bf16(al, b2h, acc2, 0, 0, 0);
            acc3 = __builtin_amdgcn_mfma_f32_16x16x32_bf16(ah, b3h, acc3, 0, 0, 0);
            acc3 = __builtin_amdgcn_mfma_f32_16x16x32_bf16(ah, b3l, acc3, 0, 0, 0);
            acc3 = __builtin_amdgcn_mfma_f32_16x16x32_bf16(al, b3h, acc3, 0, 0, 0);
        }
    }

    unsigned short* zb = (unsigned short*)z;
#pragma unroll
    for (int i = 0; i < 4; ++i) {
        int r = r0 + g * 4 + i;           // D row
        if (r < N_NODES) {
            unsigned short* zr = zb + (size_t)r * F_OUT + cb;
            zr[0]  = f2bfu(acc0[i]);
            zr[16] = f2bfu(acc1[i]);
            zr[32] = f2bfu(acc2[i]);
            zr[48] = f2bfu(acc3[i]);
        }
    }
}

// pull aggregation v6: 8 nodes per wave, 16 edges in flight per iteration
// (two srcs words per lane -> 2x memory-level parallelism; typical degree ~16
// completes in one iteration). z unscaled; acc += dinv[su]*z[su].
__global__ __launch_bounds__(256) void k_agg(const int* __restrict__ flag,
                                             const int* __restrict__ ptr,
                                             const int* __restrict__ cnt,
                                             const int* __restrict__ srcs,
                                             const float* __restrict__ dinv,
                                             const bf16* __restrict__ z,
                                             const float* __restrict__ cvec,
                                             void* __restrict__ out) {
    int wid  = (blockIdx.x * 256 + threadIdx.x) >> 6;
    int lane = threadIdx.x & 63;
    int g  = lane >> 3;          // node slot in wave
    int j8 = lane & 7;           // feature octet
    int node = wid * 8 + g;      // grid sized so node <= 99999 always when wid valid
    bool alive = node < N_NODES;
    int n = 0, start = 0;
    if (alive) { n = cnt[node]; start = ptr[node]; }
    const uint4* z4 = (const uint4*)z;

    float acc[8];
#pragma unroll
    for (int i = 0; i < 8; ++i) acc[i] = 0.f;

    for (int b = 0; __any(b < n); b += 16) {
        int s0 = 0, s1 = 0;
        int i0 = b + j8, i1 = b + 8 + j8;
        if (i0 < n) s0 = srcs[start + i0];   // lane (g,j8): edges b+j8, b+8+j8
        if (i1 < n) s1 = srcs[start + i1];
#pragma unroll
        for (int k = 0; k < 8; ++k) {
            int su = __shfl(s0, (g << 3) | k, 64);
            if (b + k < n) {
                float ds = dinv[su];
                uint4 v = z4[(size_t)su * 8 + j8];
                acc[0] += ds * bflo(v.x); acc[1] += ds * bfhi(v.x);
                acc[2] += ds * bflo(v.y); acc[3] += ds * bfhi(v.y);
                acc[4] += ds * bflo(v.z); acc[5] += ds * bfhi(v.z);
                acc[6] += ds * bflo(v.w); acc[7] += ds * bfhi(v.w);
            }
        }
#pragma unroll
        for (int k = 0; k < 8; ++k) {
            int su = __shfl(s1, (g << 3) | k, 64);
            if (b + 8 + k < n) {
                float ds = dinv[su];
                uint4 v = z4[(size_t)su * 8 + j8];
                acc[0] += ds * bflo(v.x); acc[1] += ds * bfhi(v.x);
                acc[2] += ds * bflo(v.y); acc[3] += ds * bfhi(v.y);
                acc[4] += ds * bflo(v.z); acc[5] += ds * bfhi(v.z);
                acc[6] += ds * bflo(v.w); acc[7] += ds * bfhi(v.w);
            }
        }
    }

    if (!alive) return;
    bool isbf = (*flag != 0);
    uint4 sv = z4[(size_t)node * 8 + j8];   // self-loop row (unscaled)
    float dn = dinv[node];
    const float4* cv4 = (const float4*)cvec;
    float4 c0 = cv4[j8 * 2], c1 = cv4[j8 * 2 + 1];
    size_t ob = (size_t)node * F_OUT + j8 * 8;
    if (isbf) {
        ushort4 p0, p1;
        p0.x = f2bfu(dn * (acc[0] + dn * bflo(sv.x)) + c0.x);
        p0.y = f2bfu(dn * (acc[1] + dn * bfhi(sv.x)) + c0.y);
        p0.z = f2bfu(dn * (acc[2] + dn * bflo(sv.y)) + c0.z);
        p0.w = f2bfu(dn * (acc[3] + dn * bfhi(sv.y)) + c0.w);
        p1.x = f2bfu(dn * (acc[4] + dn * bflo(sv.z)) + c1.x);
        p1.y = f2bfu(dn * (acc[5] + dn * bfhi(sv.z)) + c1.y);
        p1.z = f2bfu(dn * (acc[6] + dn * bflo(sv.w)) + c1.z);
        p1.w = f2bfu(dn * (acc[7] + dn * bfhi(sv.w)) + c1.w);
        ushort4* ob4 = (ushort4*)((unsigned short*)out + ob);
        ob4[0] = p0; ob4[1] = p1;
    } else {
        float4 q0, q1;
        q0.x = dn * (acc[0] + dn * bflo(sv.x)) + c0.x;
        q0.y = dn * (acc[1] + dn * bfhi(sv.x)) + c0.y;
        q0.z = dn * (acc[2] + dn * bflo(sv.y)) + c0.z;
        q0.w = dn * (acc[3] + dn * bfhi(sv.y)) + c0.w;
        q1.x = dn * (acc[4] + dn * bflo(sv.z)) + c1.x;
        q1.y = dn * (acc[5] + dn * bfhi(sv.z)) + c1.y;
        q1.z = dn * (acc[6] + dn * bflo(sv.w)) + c1.z;
        q1.w = dn * (acc[7] + dn * bfhi(sv.w)) + c1.w;
        float4* of4 = (float4*)((float*)out + ob);
        of4[0] = q0; of4[1] = q1;
    }
}

// ===================== fallback (atomic multi-pass) path =====================

__global__ void k_init_deg(float* __restrict__ deg) {
    int i = blockIdx.x * blockDim.x + threadIdx.x;
    if (i < N_NODES) deg[i] = 1.0f;
}
__global__ void k_deg(const int* __restrict__ col, float* __restrict__ deg) {
    int e = blockIdx.x * blockDim.x + threadIdx.x;
    if (e < N_EDGES) atomicAdd(&deg[col[e]], 1.0f);
}
__global__ void k_dinv(float* __restrict__ deg) {
    int i = blockIdx.x * blockDim.x + threadIdx.x;
    if (i < N_NODES) deg[i] = rsqrtf(deg[i]);
}
__global__ __launch_bounds__(256) void k_xm(const int* __restrict__ flag,
                                            const void* __restrict__ x,
                                            const float* __restrict__ M,
                                            void* __restrict__ z) {
    __shared__ float Ms[F_IN * F_OUT];
    int t = threadIdx.x;
    for (int i = t; i < F_IN * F_OUT; i += 256) Ms[i] = M[i];
    __syncthreads();
    bool isbf = (*flag != 0);
    int r = blockIdx.x * 4 + (t >> 6);
    int c = t & 63;
    if (r >= N_NODES) return;
    float s = 0.f;
    if (isbf) {
        const bf16* xr = (const bf16*)x + (size_t)r * F_IN;
#pragma unroll
        for (int k = 0; k < F_IN; ++k) s += __bfloat162float(xr[k]) * Ms[k * F_OUT + c];
    } else {
        const float* xr = (const float*)x + (size_t)r * F_IN;
#pragma unroll
        for (int k = 0; k < F_IN; ++k) s += xr[k] * Ms[k * F_OUT + c];
    }
    stf(z, (size_t)r * F_OUT + c, isbf, s);
}
template <int LOGF>
__global__ __launch_bounds__(256) void k_init_acc(const int* __restrict__ flag,
                                                  const float* __restrict__ dinv,
                                                  const void* __restrict__ z,
                                                  float* __restrict__ acc, int base) {
    bool isbf = (*flag != 0);
    int t = blockIdx.x * 256 + threadIdx.x;
    int i = t >> LOGF, f = t & ((1 << LOGF) - 1);
    if (i >= N_NODES) return;
    float d = dinv[i];
    acc[t] = d * d * ldf(z, (size_t)i * F_OUT + base + f, isbf);
}
template <int LOGF>
__global__ __launch_bounds__(256) void k_scatter(const int* __restrict__ flag,
                                                 const int* __restrict__ ei,
                                                 const float* __restrict__ dinv,
                                                 const void* __restrict__ z,
                                                 float* __restrict__ acc, int base) {
    bool isbf = (*flag != 0);
    long long t = (long long)blockIdx.x * 256 + threadIdx.x;
    int e = (int)(t >> LOGF), f = (int)(t & ((1 << LOGF) - 1));
    if (e >= N_EDGES) return;
    int r = ei[e], c = ei[N_EDGES + e];
    float nm = dinv[r] * dinv[c];
    float v  = nm * ldf(z, (size_t)r * F_OUT + base + f, isbf);
    atomicAdd(&acc[((size_t)c << LOGF) + f], v);
}
template <int LOGF>
__global__ __launch_bounds__(256) void k_final(const int* __restrict__ flag,
                                               const float* __restrict__ acc,
                                               const float* __restrict__ cvec,
                                               void* __restrict__ out, int base) {
    bool isbf = (*flag != 0);
    int t = blockIdx.x * 256 + threadIdx.x;
    int i = t >> LOGF, f = t & ((1 << LOGF) - 1);
    if (i >= N_NODES) return;
    stf(out, (size_t)i * F_OUT + base + f, isbf, acc[t] + cvec[base + f]);
}
template <int LOGF>
static void run_passes(const int* flag, const int* ei, const float* dinv,
                       const void* z, float* acc, const float* cvec, void* out,
                       hipStream_t stream) {
    const int fpp = 1 << LOGF;
    const long long tn = (long long)N_NODES * fpp;
    const long long te = (long long)N_EDGES * fpp;
    const int gn = (int)((tn + 255) / 256);
    const int ge = (int)((te + 255) / 256);
    for (int base = 0; base < F_OUT; base += fpp) {
        k_init_acc<LOGF><<<gn, 256, 0, stream>>>(flag, dinv, z, acc, base);
        k_scatter<LOGF><<<ge, 256, 0, stream>>>(flag, ei, dinv, z, acc, base);
        k_final<LOGF><<<gn, 256, 0, stream>>>(flag, acc, cvec, out, base);
    }
}

extern "C" void kernel_launch(void* const* d_in, const int* in_sizes, int n_in,
                              void* d_out, int out_size, void* d_ws, size_t ws_size,
                              hipStream_t stream) {
    const void* x   = d_in[0];
    const int*  ei  = (const int*)d_in[1];
    const void* Wg  = d_in[2];
    const void* bg  = d_in[3];
    const void* Wf  = d_in[4];
    const void* bfc = d_in[5];
    char* ws = (char*)d_ws;

    const size_t CSR_NEED = 27895808;
    if (ws_size >= CSR_NEED) {
        int*      flag  = (int*)(ws + 0);
        float*    dinv  = (float*)(ws + 256);
        float*    M     = (float*)(ws + 400384);
        float*    cvec  = (float*)(ws + 433152);
        int*      cnt   = (int*)(ws + 433664);
        int*      ptr   = (int*)(ws + 833664);
        int*      gtail = (int*)(ws + 1233664);
        int*      srcs  = (int*)(ws + 1238528);
        bf16*     z     = (bf16*)(ws + 8038400);
        bf16*     Mhi   = (bf16*)(ws + 20838400);
        bf16*     Mlo   = (bf16*)(ws + 20854784);
        unsigned* bkt   = (unsigned*)(ws + 20871168);

        hipMemsetAsync(gtail, 0, NB_BKT * 4, stream);
        // FAT1: 32 weights blocks || 782 binA blocks (256 thr, 2048 edges each)
        k_fat1<<<WBLK + (N_EDGES + EPB_A - 1) / EPB_A, 256, 0, stream>>>(
                    (const unsigned short*)x, Wg, bg, Wf, bfc, M, cvec, Mhi, Mlo,
                    flag, ei, gtail, bkt);
        // FAT2: 196 build blocks || 782 xmz blocks (512 thr)
        k_fat2<<<NB_BKT + XMZ_BLK, 512, 0, stream>>>(bkt, gtail, ptr, cnt, dinv,
                    srcs, flag, x, Mhi, Mlo, z);
        // 8 nodes per wave: 12500 waves = 3125 blocks of 256
        k_agg<<<3125, 256, 0, stream>>>(flag, ptr, cnt, srcs, dinv, z, cvec, d_out);
    } else {
        int*   flag = (int*)(ws + 0);
        float* deg  = (float*)(ws + 256);
        float* M    = (float*)(ws + 400384);
        float* cvec = (float*)(ws + 433152);
        float* acc  = (float*)(ws + 433664);

        // weights-only FAT1 (grid = WBLK -> binA part never runs)
        k_fat1<<<WBLK, 256, 0, stream>>>((const unsigned short*)x,
                    Wg, bg, Wf, bfc, M, cvec, (bf16*)nullptr, (bf16*)nullptr,
                    flag, (const int*)nullptr, (int*)nullptr, (unsigned*)nullptr);
        k_init_deg<<<NBLK, 256, 0, stream>>>(deg);
        k_deg<<<N_EDGES / 256, 256, 0, stream>>>(ei + N_EDGES, deg);
        k_dinv<<<NBLK, 256, 0, stream>>>(deg);
        k_xm<<<N_NODES / 4, 256, 0, stream>>>(flag, x, M, d_out);
        const size_t bn = 433664;
        if      (ws_size >= bn + (400000ull << 6)) run_passes<6>(flag, ei, deg, d_out, acc, cvec, d_out, stream);
        else if (ws_size >= bn + (400000ull << 5)) run_passes<5>(flag, ei, deg, d_out, acc, cvec, d_out, stream);
        else if (ws_size >= bn + (400000ull << 4)) run_passes<4>(flag, ei, deg, d_out, acc, cvec, d_out, stream);
        else if (ws_size >= bn + (400000ull << 3)) run_passes<3>(flag, ei, deg, d_out, acc, cvec, d_out, stream);
        else if (ws_size >= bn + (400000ull << 2)) run_passes<2>(flag, ei, deg, d_out, acc, cvec, d_out, stream);
        else if (ws_size >= bn + (400000ull << 1)) run_passes<1>(flag, ei, deg, d_out, acc, cvec, d_out, stream);
        else                                       run_passes<0>(flag, ei, deg, d_out, acc, cvec, d_out, stream);
    }
}

// Round 12
// 191.789 us; speedup vs baseline: 1.0740x; 1.0547x over previous
//
#include <hip/hip_runtime.h>
#include <hip/hip_bf16.h>

typedef __hip_bfloat16 bf16;

#define N_NODES 100000
#define N_EDGES 1600000
#define F_IN    128
#define F_OUT   64
#define NBLK    391   // ceil(100000/256)

#define NB_BKT   196    // buckets of 512 target-nodes (c>>9)
#define BKT_SH   9
#define BKT_CAP  8960   // expected 8163/bucket, +8.8 sigma
#define LBIN_CAP 56     // per-block LDS bin cap (expected 20.9, +7.7 sigma)
#define EPB_A    4096   // edges per block, phase A (16 edges/thread @256 thr)
#define WBLK     32     // weights blocks inside FAT1 (= F_IN*F_OUT/256)
#define XMZ_BLK  782    // ceil(100000/128) xmz blocks inside FAT2

// ---------------- CSR-path workspace layout (bytes) ----------------
// flag @0 (256) | dinv f32 @256 (400KB) | M @400,384 | cvec @433,152
// cnt @433,664 | ptr @833,664 | gtail @1,233,664 (784B)
// srcs int @1,238,528 (6.4MB, ends 7,638,528)
// z bf16 @8,038,400 (12.8MB, ends 20,838,400)  [z = x@M, UNSCALED]
// Mhi bf16 @20,838,400 (16KB) | Mlo bf16 @20,854,784 (16KB)
// bkt u32 @20,871,168 (7.02MB, ends 27,895,808)  [no z-alias: build||xmz overlap]
// total 27,895,808 B. Fallback (atomic multi-pass) path used if ws smaller.
//
// LESSONS (R5, R7): per-edge random global 4B stores OR atomics cost ~40-64B
// each in HBM/coherence amplification. All per-edge scatter stays LDS-staged.
// LESSON (R10/R11): binA scaling is a fixed-cost (per-block ~200 bin loop
// iters) vs contention (block width) trade-off; 256thr x 4096 edges is the
// minimum. Wider blocks (R10: +25%) and more blocks (R11: +15%) both lose.
// This round: attack the per-thread SERIAL atomic chain instead — batch all
// 16 atomicAdds before the stores (MLP 1 -> 16 on LDS-atomic latency).
// Structure: memset(gtail) -> FAT1{weights || binA-batched} ->
//            FAT2{build || xmz(z unscaled)} -> agg(16-wide, dinv FMA).

typedef __attribute__((ext_vector_type(8))) short vbf8;   // 8 bf16 = 4 VGPR
typedef __attribute__((ext_vector_type(4))) float vf4;

__device__ __forceinline__ float ldf(const void* p, size_t i, bool isbf) {
    return isbf ? __bfloat162float(((const bf16*)p)[i]) : ((const float*)p)[i];
}
__device__ __forceinline__ void stf(void* p, size_t i, bool isbf, float v) {
    if (isbf) ((bf16*)p)[i] = __float2bfloat16(v);
    else      ((float*)p)[i] = v;
}
__device__ __forceinline__ unsigned short f2bfu(float f) {
    __hip_bfloat16 h = __float2bfloat16(f);
    union { __hip_bfloat16 h; unsigned short u; } c; c.h = h; return c.u;
}
__device__ __forceinline__ float bflo(unsigned int u) { return __uint_as_float(u << 16); }
__device__ __forceinline__ float bfhi(unsigned int u) { return __uint_as_float(u & 0xffff0000u); }

// ===================== FAT1 (256 thr): weights-part || binA-part ============
// blocks [0,WBLK): M = Wg @ Wf^T, cvec, Mhi/Mlo frag-order split, flag (blk 0).
// blocks [WBLK, WBLK+391): edge bucketize. Per thread: load 16 edges, issue
//   all 16 LDS atomicAdds back-to-back (independent -> latencies overlap),
//   then the 16 stores. NO per-edge global atomics (R7 lesson).
// Mhi/Mlo layout: frag element i of lane l, tile (kk,ct) at ((kk*4+ct)*64+l)*8+i
//   holds M[kk*32 + 8*((l>>4)&3) + i][ct*16 + (l&15)]; same (l>>4,i)->k bijection
//   as the xmz A-side loads, so contraction is HW-k-order independent.
__global__ __launch_bounds__(256) void k_fat1(const unsigned short* __restrict__ xs,
                          const void* __restrict__ Wg, const void* __restrict__ bg,
                          const void* __restrict__ Wf, const void* __restrict__ bfc,
                          float* __restrict__ M, float* __restrict__ cvec,
                          bf16* __restrict__ Mhi, bf16* __restrict__ Mlo,
                          int* __restrict__ flag,
                          const int* __restrict__ ei, int* __restrict__ gtail,
                          unsigned* __restrict__ bkt) {
    __shared__ unsigned lbin[NB_BKT * LBIN_CAP];
    __shared__ int lcnt[NB_BKT];
    __shared__ int lbase[NB_BKT];
    __shared__ int sflag;
    int lt = threadIdx.x;

    if (blockIdx.x < WBLK) {
        // ---------------- weights part ----------------
        if (lt < 64) {                       // wave 0: local dtype sniff
            int good = 0;
#pragma unroll
            for (int q = 0; q < 2; ++q) {
                unsigned short v = xs[2 * (lt + 64 * q)];
                int e = (v >> 7) & 0xFF;
                if ((e >= 100 && e <= 140) || ((v & 0x7FFF) == 0)) good++;
            }
            unsigned long long m1 = __ballot(good >= 1), m2 = __ballot(good >= 2);
            if (lt == 0) sflag = (__popcll(m1) + __popcll(m2) >= 96) ? 1 : 0;
        }
        __syncthreads();
        bool isbf = (sflag != 0);
        if (blockIdx.x == 0 && lt == 0) *flag = sflag;
        int t = blockIdx.x * 256 + lt;
        int k = t >> 6, c = t & 63;
        float s = 0.f;
        for (int j = 0; j < F_IN; ++j)
            s += ldf(Wg, k * F_IN + j, isbf) * ldf(Wf, c * F_IN + j, isbf);
        M[k * F_OUT + c] = s;
        if (Mhi) {
            int l    = (((k >> 3) & 3) << 4) | (c & 15);
            int fidx = ((((k >> 5) << 2) + (c >> 4)) * 64 + l) * 8 + (k & 7);
            bf16 h  = __float2bfloat16(s);
            Mhi[fidx] = h;
            Mlo[fidx] = __float2bfloat16(s - __bfloat162float(h));
        }
        if (k == 0) {
            float cs = ldf(bfc, c, isbf);
            for (int j = 0; j < F_IN; ++j)
                cs += ldf(bg, j, isbf) * ldf(Wf, c * F_IN + j, isbf);
            cvec[c] = cs;
        }
        return;
    }

    // ---------------- binA part (batched atomics) ----------------
    int t = lt;
    for (int b = t; b < NB_BKT; b += 256) lcnt[b] = 0;
    __syncthreads();
    int v0 = (blockIdx.x - WBLK) * (EPB_A / 4);     // int4-vector index base

    unsigned val[16];
    int      bin[16];
    bool     ok[16];
    // phase 1: load 16 edges (4 int4 pairs)
#pragma unroll
    for (int q = 0; q < 4; ++q) {
        int vi = v0 + q * 256 + t;
        bool valid = (vi * 4 < N_EDGES);     // N_EDGES % 4 == 0: whole-vector guard
        int4 rv = valid ? ((const int4*)ei)[vi] : make_int4(0, 0, 0, 0);
        int4 cv = valid ? ((const int4*)(ei + N_EDGES))[vi] : make_int4(0, 0, 0, 0);
        int rs[4] = {rv.x, rv.y, rv.z, rv.w};
        int cs[4] = {cv.x, cv.y, cv.z, cv.w};
#pragma unroll
        for (int j = 0; j < 4; ++j) {
            int i = q * 4 + j;
            ok[i]  = valid;
            bin[i] = cs[j] >> BKT_SH;
            val[i] = (unsigned)rs[j] |
                     ((unsigned)(cs[j] & ((1 << BKT_SH) - 1)) << 17);
        }
    }
    // phase 2: issue all 16 atomicAdds (independent -> overlapped latency)
    int p[16];
#pragma unroll
    for (int i = 0; i < 16; ++i)
        p[i] = ok[i] ? atomicAdd(&lcnt[bin[i]], 1) : 0;
    // phase 3: stores
#pragma unroll
    for (int i = 0; i < 16; ++i) {
        if (ok[i]) {
            if (p[i] < LBIN_CAP) {
                lbin[bin[i] * LBIN_CAP + p[i]] = val[i];
            } else {                          // rare overflow: direct global
                int gp = atomicAdd(&gtail[bin[i]], 1);
                if (gp < BKT_CAP) bkt[(size_t)bin[i] * BKT_CAP + gp] = val[i];
            }
        }
    }
    __syncthreads();
    for (int b = t; b < NB_BKT; b += 256) {
        int n = min(lcnt[b], LBIN_CAP);
        lbase[b] = atomicAdd(&gtail[b], n);
    }
    __syncthreads();
    // flush: wave w owns bins w, w+4, ... (no integer division)
    int w = t >> 6, l = t & 63;
    for (int b = w; b < NB_BKT; b += 4) {
        int nB = min(lcnt[b], LBIN_CAP);
        int gp0 = lbase[b];
        for (int i = l; i < nB; i += 64) {
            int gp = gp0 + i;
            if (gp < BKT_CAP) bkt[(size_t)b * BKT_CAP + gp] = lbin[b * LBIN_CAP + i];
        }
    }
}

// ===================== FAT2: build-part || xmz-part =====================
// blocks [0,NB_BKT): per-bucket base (gtail reduce) -> LDS histogram -> scan
//   -> ptr/cnt/dinv -> place srcs (LDS-windowed scatter).
// blocks [NB_BKT, NB_BKT+XMZ_BLK): z = x@M via MFMA, 512 thr / 128 rows.
//   z is UNSCALED (dinv applied in k_agg) — no dependence on the build part;
//   the two halves overlap freely across CUs.
__global__ __launch_bounds__(512) void k_fat2(const unsigned* __restrict__ bkt,
                                              const int* __restrict__ gtail,
                                              int* __restrict__ ptr,
                                              int* __restrict__ cnt,
                                              float* __restrict__ dinv,
                                              int* __restrict__ srcs,
                                              const int* __restrict__ flag,
                                              const void* __restrict__ x,
                                              const bf16* __restrict__ Mhi,
                                              const bf16* __restrict__ Mlo,
                                              bf16* __restrict__ z) {
    __shared__ int cntl[512], sm[512], fill[512];
    int t = threadIdx.x;

    if (blockIdx.x < NB_BKT) {
        // ---------------- build part ----------------
        int b = blockIdx.x;
        int n = min(gtail[b], BKT_CAP);
        // base = sum_{b'<b} min(gtail[b'], BKT_CAP): 512-wide masked tree reduce
        int gv = (t < b) ? min(gtail[t], BKT_CAP) : 0;   // t<b<=195 implies t<NB_BKT
        sm[t] = gv; __syncthreads();
#pragma unroll
        for (int s = 256; s >= 1; s >>= 1) {
            if (t < s) sm[t] += sm[t + s];
            __syncthreads();
        }
        int base = sm[0];
        cntl[t] = 0;
        __syncthreads();
        for (int i = t; i < n; i += 512)
            atomicAdd(&cntl[bkt[(size_t)b * BKT_CAP + i] >> 17], 1);
        __syncthreads();
        int v = cntl[t];
        sm[t] = v; __syncthreads();
        for (int s = 1; s < 512; s <<= 1) {
            int add = (t >= s) ? sm[t - s] : 0;
            __syncthreads();
            sm[t] += add;
            __syncthreads();
        }
        int excl = sm[t] - v;
        fill[t] = excl;
        int node = (b << BKT_SH) + t;
        if (node < N_NODES) {
            ptr[node]  = base + excl;
            cnt[node]  = v;
            dinv[node] = rsqrtf((float)(v + 1));   // +1 self-loop
        }
        __syncthreads();
        for (int i = t; i < n; i += 512) {
            unsigned e = bkt[(size_t)b * BKT_CAP + i];
            int c = (int)(e >> 17);
            int p = atomicAdd(&fill[c], 1);        // LDS atomic
            srcs[base + p] = (int)(e & 0x1FFFF);
        }
        return;
    }

    // ---------------- xmz part (512 thr, 128 rows/block) ----------------
    // bf16 world: A frags straight from x, 2 MFMAs/tile (Mh,Ml).
    // fp32 world: trunc-split xh+xl (~2^-16), 3 MFMAs/tile (xh*Mh+xh*Ml+xl*Mh).
    // D layout (m89-verified): col = lane&15, row = (lane>>4)*4 + reg.
    int bid = blockIdx.x - NB_BKT;
    int w = t >> 6, lane = t & 63;
    int g = lane >> 4, cb = lane & 15;
    int r0 = bid * 128 + w * 16;          // wave's 16-row base
    int rr = min(r0 + cb, N_NODES - 1);   // A-fragment row (clamped dup for tail)
    bool isbf = (*flag != 0);
    const vbf8* Bh = (const vbf8*)Mhi;
    const vbf8* Bl = (const vbf8*)Mlo;
    vf4 acc0 = {0.f,0.f,0.f,0.f}, acc1 = {0.f,0.f,0.f,0.f};
    vf4 acc2 = {0.f,0.f,0.f,0.f}, acc3 = {0.f,0.f,0.f,0.f};

    if (isbf) {
        const vbf8* X8 = (const vbf8*)x;
#pragma unroll
        for (int kk = 0; kk < 4; ++kk) {
            vbf8 a = X8[(size_t)rr * 16 + kk * 4 + g];   // row rr, k = 32kk + 8g + [0..7]
            int bb = kk * 256 + lane;                    // (kk*4 + ct)*64 + lane
            acc0 = __builtin_amdgcn_mfma_f32_16x16x32_bf16(a, Bh[bb      ], acc0, 0, 0, 0);
            acc0 = __builtin_amdgcn_mfma_f32_16x16x32_bf16(a, Bl[bb      ], acc0, 0, 0, 0);
            acc1 = __builtin_amdgcn_mfma_f32_16x16x32_bf16(a, Bh[bb +  64], acc1, 0, 0, 0);
            acc1 = __builtin_amdgcn_mfma_f32_16x16x32_bf16(a, Bl[bb +  64], acc1, 0, 0, 0);
            acc2 = __builtin_amdgcn_mfma_f32_16x16x32_bf16(a, Bh[bb + 128], acc2, 0, 0, 0);
            acc2 = __builtin_amdgcn_mfma_f32_16x16x32_bf16(a, Bl[bb + 128], acc2, 0, 0, 0);
            acc3 = __builtin_amdgcn_mfma_f32_16x16x32_bf16(a, Bh[bb + 192], acc3, 0, 0, 0);
            acc3 = __builtin_amdgcn_mfma_f32_16x16x32_bf16(a, Bl[bb + 192], acc3, 0, 0, 0);
        }
    } else {
        const float4* X4 = (const float4*)x;
#pragma unroll
        for (int kk = 0; kk < 4; ++kk) {
            float4 v0 = X4[(size_t)rr * 32 + kk * 8 + g * 2];      // k = 32kk+8g+[0..3]
            float4 v1 = X4[(size_t)rr * 32 + kk * 8 + g * 2 + 1];  // k = 32kk+8g+[4..7]
            vbf8 ah, al;
            {
                float fv[8] = {v0.x, v0.y, v0.z, v0.w, v1.x, v1.y, v1.z, v1.w};
#pragma unroll
                for (int i = 0; i < 8; ++i) {
                    unsigned bi = __float_as_uint(fv[i]);
                    ah[i] = (short)(bi >> 16);                         // trunc hi
                    float r = fv[i] - __uint_as_float(bi & 0xffff0000u);
                    al[i] = (short)(__float_as_uint(r) >> 16);         // trunc lo
                }
            }
            int bb = kk * 256 + lane;
            vbf8 b0h = Bh[bb      ], b0l = Bl[bb      ];
            vbf8 b1h = Bh[bb +  64], b1l = Bl[bb +  64];
            vbf8 b2h = Bh[bb + 128], b2l = Bl[bb + 128];
            vbf8 b3h = Bh[bb + 192], b3l = Bl[bb + 192];
            acc0 = __builtin_amdgcn_mfma_f32_16x16x32_bf16(ah, b0h, acc0, 0, 0, 0);
            acc0 = __builtin_amdgcn_mfma_f32_16x16x32_bf16(ah, b0l, acc0, 0, 0, 0);
            acc0 = __builtin_amdgcn_mfma_f32_16x16x32_bf16(al, b0h, acc0, 0, 0, 0);
            acc1 = __builtin_amdgcn_mfma_f32_16x16x32_bf16(ah, b1h, acc1, 0, 0, 0);
            acc1 = __builtin_amdgcn_mfma_f32_16x16x32_bf16(ah, b1l, acc1, 0, 0, 0);
            acc1 = __builtin_amdgcn_mfma_f32_16x16x32_bf16(al, b1h, acc1, 0, 0, 0);
            acc2 = __builtin_amdgcn_mfma_f32_16x16x32_bf16(ah, b2h, acc2, 0, 0, 0);
            acc2 = __builtin_amdgcn_mfma_f32_16x16x32_bf16(ah, b2l, acc2, 0, 0, 0);
            acc2 = __builtin_amdgcn_mfma_f32_16x16x32_bf16(al, b2h, acc2, 0, 0, 0);
            acc3 = __builtin_amdgcn_mfma_f32_16x16x32_bf16(ah, b3h, acc3, 0, 0, 0);
            acc3 = __builtin_amdgcn_mfma_f32_16x16x32_bf16(ah, b3l, acc3, 0, 0, 0);
            acc3 = __builtin_amdgcn_mfma_f32_16x16x32_bf16(al, b3h, acc3, 0, 0, 0);
        }
    }

    unsigned short* zb = (unsigned short*)z;
#pragma unroll
    for (int i = 0; i < 4; ++i) {
        int r = r0 + g * 4 + i;           // D row
        if (r < N_NODES) {
            unsigned short* zr = zb + (size_t)r * F_OUT + cb;
            zr[0]  = f2bfu(acc0[i]);
            zr[16] = f2bfu(acc1[i]);
            zr[32] = f2bfu(acc2[i]);
            zr[48] = f2bfu(acc3[i]);
        }
    }
}

// pull aggregation v6: 8 nodes per wave, 16 edges in flight per iteration
// (two srcs words per lane -> 2x memory-level parallelism; typical degree ~16
// completes in one iteration). z unscaled; acc += dinv[su]*z[su].
__global__ __launch_bounds__(256) void k_agg(const int* __restrict__ flag,
                                             const int* __restrict__ ptr,
                                             const int* __restrict__ cnt,
                                             const int* __restrict__ srcs,
                                             const float* __restrict__ dinv,
                                             const bf16* __restrict__ z,
                                             const float* __restrict__ cvec,
                                             void* __restrict__ out) {
    int wid  = (blockIdx.x * 256 + threadIdx.x) >> 6;
    int lane = threadIdx.x & 63;
    int g  = lane >> 3;          // node slot in wave
    int j8 = lane & 7;           // feature octet
    int node = wid * 8 + g;      // grid sized so node <= 99999 always when wid valid
    bool alive = node < N_NODES;
    int n = 0, start = 0;
    if (alive) { n = cnt[node]; start = ptr[node]; }
    const uint4* z4 = (const uint4*)z;

    float acc[8];
#pragma unroll
    for (int i = 0; i < 8; ++i) acc[i] = 0.f;

    for (int b = 0; __any(b < n); b += 16) {
        int s0 = 0, s1 = 0;
        int i0 = b + j8, i1 = b + 8 + j8;
        if (i0 < n) s0 = srcs[start + i0];   // lane (g,j8): edges b+j8, b+8+j8
        if (i1 < n) s1 = srcs[start + i1];
#pragma unroll
        for (int k = 0; k < 8; ++k) {
            int su = __shfl(s0, (g << 3) | k, 64);
            if (b + k < n) {
                float ds = dinv[su];
                uint4 v = z4[(size_t)su * 8 + j8];
                acc[0] += ds * bflo(v.x); acc[1] += ds * bfhi(v.x);
                acc[2] += ds * bflo(v.y); acc[3] += ds * bfhi(v.y);
                acc[4] += ds * bflo(v.z); acc[5] += ds * bfhi(v.z);
                acc[6] += ds * bflo(v.w); acc[7] += ds * bfhi(v.w);
            }
        }
#pragma unroll
        for (int k = 0; k < 8; ++k) {
            int su = __shfl(s1, (g << 3) | k, 64);
            if (b + 8 + k < n) {
                float ds = dinv[su];
                uint4 v = z4[(size_t)su * 8 + j8];
                acc[0] += ds * bflo(v.x); acc[1] += ds * bfhi(v.x);
                acc[2] += ds * bflo(v.y); acc[3] += ds * bfhi(v.y);
                acc[4] += ds * bflo(v.z); acc[5] += ds * bfhi(v.z);
                acc[6] += ds * bflo(v.w); acc[7] += ds * bfhi(v.w);
            }
        }
    }

    if (!alive) return;
    bool isbf = (*flag != 0);
    uint4 sv = z4[(size_t)node * 8 + j8];   // self-loop row (unscaled)
    float dn = dinv[node];
    const float4* cv4 = (const float4*)cvec;
    float4 c0 = cv4[j8 * 2], c1 = cv4[j8 * 2 + 1];
    size_t ob = (size_t)node * F_OUT + j8 * 8;
    if (isbf) {
        ushort4 p0, p1;
        p0.x = f2bfu(dn * (acc[0] + dn * bflo(sv.x)) + c0.x);
        p0.y = f2bfu(dn * (acc[1] + dn * bfhi(sv.x)) + c0.y);
        p0.z = f2bfu(dn * (acc[2] + dn * bflo(sv.y)) + c0.z);
        p0.w = f2bfu(dn * (acc[3] + dn * bfhi(sv.y)) + c0.w);
        p1.x = f2bfu(dn * (acc[4] + dn * bflo(sv.z)) + c1.x);
        p1.y = f2bfu(dn * (acc[5] + dn * bfhi(sv.z)) + c1.y);
        p1.z = f2bfu(dn * (acc[6] + dn * bflo(sv.w)) + c1.z);
        p1.w = f2bfu(dn * (acc[7] + dn * bfhi(sv.w)) + c1.w);
        ushort4* ob4 = (ushort4*)((unsigned short*)out + ob);
        ob4[0] = p0; ob4[1] = p1;
    } else {
        float4 q0, q1;
        q0.x = dn * (acc[0] + dn * bflo(sv.x)) + c0.x;
        q0.y = dn * (acc[1] + dn * bfhi(sv.x)) + c0.y;
        q0.z = dn * (acc[2] + dn * bflo(sv.y)) + c0.z;
        q0.w = dn * (acc[3] + dn * bfhi(sv.y)) + c0.w;
        q1.x = dn * (acc[4] + dn * bflo(sv.z)) + c1.x;
        q1.y = dn * (acc[5] + dn * bfhi(sv.z)) + c1.y;
        q1.z = dn * (acc[6] + dn * bflo(sv.w)) + c1.z;
        q1.w = dn * (acc[7] + dn * bfhi(sv.w)) + c1.w;
        float4* of4 = (float4*)((float*)out + ob);
        of4[0] = q0; of4[1] = q1;
    }
}

// ===================== fallback (atomic multi-pass) path =====================

__global__ void k_init_deg(float* __restrict__ deg) {
    int i = blockIdx.x * blockDim.x + threadIdx.x;
    if (i < N_NODES) deg[i] = 1.0f;
}
__global__ void k_deg(const int* __restrict__ col, float* __restrict__ deg) {
    int e = blockIdx.x * blockDim.x + threadIdx.x;
    if (e < N_EDGES) atomicAdd(&deg[col[e]], 1.0f);
}
__global__ void k_dinv(float* __restrict__ deg) {
    int i = blockIdx.x * blockDim.x + threadIdx.x;
    if (i < N_NODES) deg[i] = rsqrtf(deg[i]);
}
__global__ __launch_bounds__(256) void k_xm(const int* __restrict__ flag,
                                            const void* __restrict__ x,
                                            const float* __restrict__ M,
                                            void* __restrict__ z) {
    __shared__ float Ms[F_IN * F_OUT];
    int t = threadIdx.x;
    for (int i = t; i < F_IN * F_OUT; i += 256) Ms[i] = M[i];
    __syncthreads();
    bool isbf = (*flag != 0);
    int r = blockIdx.x * 4 + (t >> 6);
    int c = t & 63;
    if (r >= N_NODES) return;
    float s = 0.f;
    if (isbf) {
        const bf16* xr = (const bf16*)x + (size_t)r * F_IN;
#pragma unroll
        for (int k = 0; k < F_IN; ++k) s += __bfloat162float(xr[k]) * Ms[k * F_OUT + c];
    } else {
        const float* xr = (const float*)x + (size_t)r * F_IN;
#pragma unroll
        for (int k = 0; k < F_IN; ++k) s += xr[k] * Ms[k * F_OUT + c];
    }
    stf(z, (size_t)r * F_OUT + c, isbf, s);
}
template <int LOGF>
__global__ __launch_bounds__(256) void k_init_acc(const int* __restrict__ flag,
                                                  const float* __restrict__ dinv,
                                                  const void* __restrict__ z,
                                                  float* __restrict__ acc, int base) {
    bool isbf = (*flag != 0);
    int t = blockIdx.x * 256 + threadIdx.x;
    int i = t >> LOGF, f = t & ((1 << LOGF) - 1);
    if (i >= N_NODES) return;
    float d = dinv[i];
    acc[t] = d * d * ldf(z, (size_t)i * F_OUT + base + f, isbf);
}
template <int LOGF>
__global__ __launch_bounds__(256) void k_scatter(const int* __restrict__ flag,
                                                 const int* __restrict__ ei,
                                                 const float* __restrict__ dinv,
                                                 const void* __restrict__ z,
                                                 float* __restrict__ acc, int base) {
    bool isbf = (*flag != 0);
    long long t = (long long)blockIdx.x * 256 + threadIdx.x;
    int e = (int)(t >> LOGF), f = (int)(t & ((1 << LOGF) - 1));
    if (e >= N_EDGES) return;
    int r = ei[e], c = ei[N_EDGES + e];
    float nm = dinv[r] * dinv[c];
    float v  = nm * ldf(z, (size_t)r * F_OUT + base + f, isbf);
    atomicAdd(&acc[((size_t)c << LOGF) + f], v);
}
template <int LOGF>
__global__ __launch_bounds__(256) void k_final(const int* __restrict__ flag,
                                               const float* __restrict__ acc,
                                               const float* __restrict__ cvec,
                                               void* __restrict__ out, int base) {
    bool isbf = (*flag != 0);
    int t = blockIdx.x * 256 + threadIdx.x;
    int i = t >> LOGF, f = t & ((1 << LOGF) - 1);
    if (i >= N_NODES) return;
    stf(out, (size_t)i * F_OUT + base + f, isbf, acc[t] + cvec[base + f]);
}
template <int LOGF>
static void run_passes(const int* flag, const int* ei, const float* dinv,
                       const void* z, float* acc, const float* cvec, void* out,
                       hipStream_t stream) {
    const int fpp = 1 << LOGF;
    const long long tn = (long long)N_NODES * fpp;
    const long long te = (long long)N_EDGES * fpp;
    const int gn = (int)((tn + 255) / 256);
    const int ge = (int)((te + 255) / 256);
    for (int base = 0; base < F_OUT; base += fpp) {
        k_init_acc<LOGF><<<gn, 256, 0, stream>>>(flag, dinv, z, acc, base);
        k_scatter<LOGF><<<ge, 256, 0, stream>>>(flag, ei, dinv, z, acc, base);
        k_final<LOGF><<<gn, 256, 0, stream>>>(flag, acc, cvec, out, base);
    }
}

extern "C" void kernel_launch(void* const* d_in, const int* in_sizes, int n_in,
                              void* d_out, int out_size, void* d_ws, size_t ws_size,
                              hipStream_t stream) {
    const void* x   = d_in[0];
    const int*  ei  = (const int*)d_in[1];
    const void* Wg  = d_in[2];
    const void* bg  = d_in[3];
    const void* Wf  = d_in[4];
    const void* bfc = d_in[5];
    char* ws = (char*)d_ws;

    const size_t CSR_NEED = 27895808;
    if (ws_size >= CSR_NEED) {
        int*      flag  = (int*)(ws + 0);
        float*    dinv  = (float*)(ws + 256);
        float*    M     = (float*)(ws + 400384);
        float*    cvec  = (float*)(ws + 433152);
        int*      cnt   = (int*)(ws + 433664);
        int*      ptr   = (int*)(ws + 833664);
        int*      gtail = (int*)(ws + 1233664);
        int*      srcs  = (int*)(ws + 1238528);
        bf16*     z     = (bf16*)(ws + 8038400);
        bf16*     Mhi   = (bf16*)(ws + 20838400);
        bf16*     Mlo   = (bf16*)(ws + 20854784);
        unsigned* bkt   = (unsigned*)(ws + 20871168);

        hipMemsetAsync(gtail, 0, NB_BKT * 4, stream);
        // FAT1: 32 weights blocks || 391 binA blocks (256 thr, batched atomics)
        k_fat1<<<WBLK + (N_EDGES + EPB_A - 1) / EPB_A, 256, 0, stream>>>(
                    (const unsigned short*)x, Wg, bg, Wf, bfc, M, cvec, Mhi, Mlo,
                    flag, ei, gtail, bkt);
        // FAT2: 196 build blocks || 782 xmz blocks (512 thr)
        k_fat2<<<NB_BKT + XMZ_BLK, 512, 0, stream>>>(bkt, gtail, ptr, cnt, dinv,
                    srcs, flag, x, Mhi, Mlo, z);
        // 8 nodes per wave: 12500 waves = 3125 blocks of 256
        k_agg<<<3125, 256, 0, stream>>>(flag, ptr, cnt, srcs, dinv, z, cvec, d_out);
    } else {
        int*   flag = (int*)(ws + 0);
        float* deg  = (float*)(ws + 256);
        float* M    = (float*)(ws + 400384);
        float* cvec = (float*)(ws + 433152);
        float* acc  = (float*)(ws + 433664);

        // weights-only FAT1 (grid = WBLK -> binA part never runs)
        k_fat1<<<WBLK, 256, 0, stream>>>((const unsigned short*)x,
                    Wg, bg, Wf, bfc, M, cvec, (bf16*)nullptr, (bf16*)nullptr,
                    flag, (const int*)nullptr, (int*)nullptr, (unsigned*)nullptr);
        k_init_deg<<<NBLK, 256, 0, stream>>>(deg);
        k_deg<<<N_EDGES / 256, 256, 0, stream>>>(ei + N_EDGES, deg);
        k_dinv<<<NBLK, 256, 0, stream>>>(deg);
        k_xm<<<N_NODES / 4, 256, 0, stream>>>(flag, x, M, d_out);
        const size_t bn = 433664;
        if      (ws_size >= bn + (400000ull << 6)) run_passes<6>(flag, ei, deg, d_out, acc, cvec, d_out, stream);
        else if (ws_size >= bn + (400000ull << 5)) run_passes<5>(flag, ei, deg, d_out, acc, cvec, d_out, stream);
        else if (ws_size >= bn + (400000ull << 4)) run_passes<4>(flag, ei, deg, d_out, acc, cvec, d_out, stream);
        else if (ws_size >= bn + (400000ull << 3)) run_passes<3>(flag, ei, deg, d_out, acc, cvec, d_out, stream);
        else if (ws_size >= bn + (400000ull << 2)) run_passes<2>(flag, ei, deg, d_out, acc, cvec, d_out, stream);
        else if (ws_size >= bn + (400000ull << 1)) run_passes<1>(flag, ei, deg, d_out, acc, cvec, d_out, stream);
        else                                       run_passes<0>(flag, ei, deg, d_out, acc, cvec, d_out, stream);
    }
}